// Round 3
// baseline (223.233 us; speedup 1.0000x reference)
//
#include <hip/hip_runtime.h>
#include <hip/hip_bf16.h>

// CRF NLL, B=256, T=1024, L=64. Linear-domain recursion with V=exp(trans) held in
// 64 *named* scalar registers per lane (macro-scalarized so nothing can demote it
// to scratch/AGPR). Meet-in-the-middle: fwd wave computes alpha_h, bwd wave beta_h,
// Z = alpha_h . beta_h. Exact power-of-2 renorm per step (IEEE exponent of lane 0,
// accumulated as int). Kernel 1 (768 one-wave blocks): fwd / bwd / gold roles.
// Kernel 2 (256 blocks): combine dot + log2.

#define RL_F(x, i) __uint_as_float(__builtin_amdgcn_readlane(__float_as_uint(x), (i)))
#define L2E 1.44269504088896340736f
#define LN2 0.69314718055994530942f

#define V_ALL(M) M(0) M(1) M(2) M(3) M(4) M(5) M(6) M(7) M(8) M(9) M(10) M(11) \
 M(12) M(13) M(14) M(15) M(16) M(17) M(18) M(19) M(20) M(21) M(22) M(23) M(24) \
 M(25) M(26) M(27) M(28) M(29) M(30) M(31) M(32) M(33) M(34) M(35) M(36) M(37) \
 M(38) M(39) M(40) M(41) M(42) M(43) M(44) M(45) M(46) M(47) M(48) M(49) M(50) \
 M(51) M(52) M(53) M(54) M(55) M(56) M(57) M(58) M(59) M(60) M(61) M(62) M(63)

#define DECLV(q) float V##q;
#define LOADF(q) V##q = __builtin_amdgcn_exp2f(tcol[(q) * 66] * L2E);
#define LOADB(q) V##q = __builtin_amdgcn_exp2f(trow[(q)] * L2E);

#define FMA4(a,b,c,d) \
    s0 = fmaf(RL_F(x,a), V##a, s0); s1 = fmaf(RL_F(x,b), V##b, s1); \
    s2 = fmaf(RL_F(x,c), V##c, s2); s3 = fmaf(RL_F(x,d), V##d, s3);
#define FMA_ALL \
    FMA4(0,1,2,3)     FMA4(4,5,6,7)     FMA4(8,9,10,11)   FMA4(12,13,14,15) \
    FMA4(16,17,18,19) FMA4(20,21,22,23) FMA4(24,25,26,27) FMA4(28,29,30,31) \
    FMA4(32,33,34,35) FMA4(36,37,38,39) FMA4(40,41,42,43) FMA4(44,45,46,47) \
    FMA4(48,49,50,51) FMA4(52,53,54,55) FMA4(56,57,58,59) FMA4(60,61,62,63)

#define ROWF(i) pb[(((i) < 0) ? 0 : (((i) > 1023) ? 1023 : (i))) * 64]

// One recursion step. fwd: a' = E .* (V^T a); bwd: a' = V (E .* a).
#define STEPM(p) { \
    float E = __builtin_amdgcn_exp2f((p) * L2E); \
    float x = FWD ? a : a * E; \
    float s0 = 0.f, s1 = 0.f, s2 = 0.f, s3 = 0.f; \
    FMA_ALL \
    float s = (s0 + s1) + (s2 + s3); \
    a = FWD ? s * E : s; \
    unsigned abits = (unsigned)__builtin_amdgcn_readfirstlane((int)__float_as_uint(a)); \
    int k = (int)((abits >> 23) & 255u) - 127; \
    K += k; \
    a *= __uint_as_float((unsigned)(127 - k) << 23); }

template<bool FWD>
__device__ __forceinline__ void chain(const float* __restrict__ pred,
                                      const float* __restrict__ trans,
                                      int b, int lane, int sl, int h,
                                      float* __restrict__ wsV,
                                      int* __restrict__ wsK)
{
    const float* pb   = pred + (size_t)b * 65536 + lane;
    const float* tcol = trans + lane;        // fwd: V[q][lane] = trans[q*66+lane]
    const float* trow = trans + lane * 66;   // bwd: V[lane][q] = trans[lane*66+q]
    (void)tcol; (void)trow;

    V_ALL(DECLV)
    if (FWD) { V_ALL(LOADF) } else { V_ALL(LOADB) }

    float a;
    int   K = 0;
    if (FWD) a = __builtin_amdgcn_exp2f((pb[0] + trans[64 * 66 + lane]) * L2E);
    else     a = __builtin_amdgcn_exp2f(trow[65] * L2E);

    const int dir = FWD ? 1 : -1;
    int n = FWD ? h - 1 : sl - h;
    int r = FWD ? 1 : sl - 1;

    float p0 = ROWF(r), p1 = ROWF(r + dir), p2 = ROWF(r + 2 * dir), p3 = ROWF(r + 3 * dir);
    while (n >= 4) {
        float q0 = ROWF(r + 4 * dir), q1 = ROWF(r + 5 * dir),
              q2 = ROWF(r + 6 * dir), q3 = ROWF(r + 7 * dir);
        STEPM(p0) STEPM(p1) STEPM(p2) STEPM(p3)
        p0 = q0; p1 = q1; p2 = q2; p3 = q3;
        r += 4 * dir; n -= 4;
    }
    if (n > 0) { STEPM(p0) --n; }
    if (n > 0) { STEPM(p1) --n; }
    if (n > 0) { STEPM(p2) }

    wsV[b * 64 + lane] = a;
    if (lane == 0) wsK[b] = K;
}

__global__ __launch_bounds__(64, 1) __attribute__((amdgpu_waves_per_eu(1)))
void chain_kernel(const float* __restrict__ pred,
                  const float* __restrict__ trans,
                  const int*   __restrict__ ref,
                  const int*   __restrict__ seqlen,
                  float* __restrict__ wsA, float* __restrict__ wsB,
                  int* __restrict__ wsKf, int* __restrict__ wsKb,
                  float* __restrict__ out)
{
    const int role = blockIdx.x >> 8;
    const int b    = blockIdx.x & 255;
    const int lane = threadIdx.x;
    const int sl   = seqlen[b];
    const int h    = (sl + 1) >> 1;

    if (role == 0) {
        chain<true>(pred, trans, b, lane, sl, h, wsA, wsKf);
    } else if (role == 1) {
        chain<false>(pred, trans, b, lane, sl, h, wsB, wsKb);
    } else {
        // gold-path score
        const int*   rb = ref  + b * 1024;
        const float* pg = pred + (size_t)b * 65536;
        float acc = 0.f;
        for (int t = lane; t <= sl; t += 64) {
            int from = (t == 0) ? 64 : rb[t - 1];
            int cur  = (t < sl) ? rb[t] : 65;
            acc += trans[from * 66 + cur];
            if (t < sl) acc += pg[t * 64 + cur];
        }
        #pragma unroll
        for (int off = 32; off; off >>= 1) acc += __shfl_xor(acc, off, 64);
        if (lane == 0) atomicAdd(out, -acc);
    }
}

__global__ __launch_bounds__(64) void combine_kernel(
    const float* __restrict__ wsA, const float* __restrict__ wsB,
    const int* __restrict__ wsKf, const int* __restrict__ wsKb,
    float* __restrict__ out)
{
    const int b = blockIdx.x, lane = threadIdx.x;
    float z = wsA[b * 64 + lane] * wsB[b * 64 + lane];
    #pragma unroll
    for (int off = 32; off; off >>= 1) z += __shfl_xor(z, off, 64);
    if (lane == 0) {
        float res = LN2 * (__builtin_amdgcn_logf(z) + (float)(wsKf[b] + wsKb[b]));
        atomicAdd(out, res);
    }
}

extern "C" void kernel_launch(void* const* d_in, const int* in_sizes, int n_in,
                              void* d_out, int out_size, void* d_ws, size_t ws_size,
                              hipStream_t stream) {
    const float* pred   = (const float*)d_in[0];
    const float* trans  = (const float*)d_in[1];
    const int*   ref    = (const int*)d_in[2];
    const int*   seqlen = (const int*)d_in[3];
    float* out = (float*)d_out;

    float* wsA  = (float*)d_ws;            // 256*64 f32
    float* wsB  = wsA + 256 * 64;          // 256*64 f32
    int*   wsKf = (int*)(wsB + 256 * 64);  // 256 i32
    int*   wsKb = wsKf + 256;              // 256 i32

    hipMemsetAsync(out, 0, sizeof(float), stream);
    chain_kernel<<<768, 64, 0, stream>>>(pred, trans, ref, seqlen,
                                         wsA, wsB, wsKf, wsKb, out);
    combine_kernel<<<256, 64, 0, stream>>>(wsA, wsB, wsKf, wsKb, out);
}

// Round 4
// 209.485 us; speedup vs baseline: 1.0656x; 1.0656x over previous
//
#include <hip/hip_runtime.h>
#include <hip/hip_bf16.h>

// CRF NLL, B=256, T=1024, L=64. Linear-domain recursion, V=exp(trans) pinned into
// 64 real VGPRs via opaque asm ("+v") + amdgpu_waves_per_eu(1,1) (full register
// budget) so RA cannot rematerialize the table from L1 every step. Meet-in-the-
// middle: fwd wave -> alpha_h, bwd wave -> beta_h, Z = alpha_h . beta_h.
// Exact power-of-2 renorm every 4 steps (IEEE exponent of lane 0, K accumulated
// as int). Kernel 1 (768 one-wave blocks): fwd / bwd / gold. Kernel 2: combine.

#define RL_F(x, i) __uint_as_float(__builtin_amdgcn_readlane(__float_as_uint(x), (i)))
#define L2E 1.44269504088896340736f
#define LN2 0.69314718055994530942f

#define V_ALL(M) M(0) M(1) M(2) M(3) M(4) M(5) M(6) M(7) M(8) M(9) M(10) M(11) \
 M(12) M(13) M(14) M(15) M(16) M(17) M(18) M(19) M(20) M(21) M(22) M(23) M(24) \
 M(25) M(26) M(27) M(28) M(29) M(30) M(31) M(32) M(33) M(34) M(35) M(36) M(37) \
 M(38) M(39) M(40) M(41) M(42) M(43) M(44) M(45) M(46) M(47) M(48) M(49) M(50) \
 M(51) M(52) M(53) M(54) M(55) M(56) M(57) M(58) M(59) M(60) M(61) M(62) M(63)

#define DECLV(q) float V##q;
#define LOADF(q) V##q = __builtin_amdgcn_exp2f(tcol[(q) * 66] * L2E);
#define LOADB(q) V##q = __builtin_amdgcn_exp2f(trow[(q)] * L2E);
#define PINV(q)  asm volatile("" : "+v"(V##q));

#define FMA4(a,b,c,d) \
    s0 = fmaf(RL_F(x,a), V##a, s0); s1 = fmaf(RL_F(x,b), V##b, s1); \
    s2 = fmaf(RL_F(x,c), V##c, s2); s3 = fmaf(RL_F(x,d), V##d, s3);
#define FMA_ALL \
    FMA4(0,1,2,3)     FMA4(4,5,6,7)     FMA4(8,9,10,11)   FMA4(12,13,14,15) \
    FMA4(16,17,18,19) FMA4(20,21,22,23) FMA4(24,25,26,27) FMA4(28,29,30,31) \
    FMA4(32,33,34,35) FMA4(36,37,38,39) FMA4(40,41,42,43) FMA4(44,45,46,47) \
    FMA4(48,49,50,51) FMA4(52,53,54,55) FMA4(56,57,58,59) FMA4(60,61,62,63)

#define ROWF(i) pb[(((i) < 0) ? 0 : (((i) > 1023) ? 1023 : (i))) * 64]
#define EXPE(p) __builtin_amdgcn_exp2f((p) * L2E)

// One step, no renorm. fwd: a' = E .* (V^T a); bwd: a' = V (E .* a).
#define STEPN(E) { \
    float x = FWD ? a : a * (E); \
    float s0 = 0.f, s1 = 0.f, s2 = 0.f, s3 = 0.f; \
    FMA_ALL \
    float s = (s0 + s1) + (s2 + s3); \
    a = FWD ? s * (E) : s; }

// Exact renorm by 2^-k, k = IEEE exponent of lane 0's a.
#define RENORM { \
    unsigned abits = (unsigned)__builtin_amdgcn_readfirstlane((int)__float_as_uint(a)); \
    int k = (int)((abits >> 23) & 255u) - 127; \
    K += k; \
    a *= __uint_as_float((unsigned)(127 - k) << 23); }

template<bool FWD>
__device__ __forceinline__ void chain(const float* __restrict__ pred,
                                      const float* __restrict__ trans,
                                      int b, int lane, int sl, int h,
                                      float* __restrict__ wsV,
                                      int* __restrict__ wsK)
{
    const float* pb   = pred + (size_t)b * 65536 + lane;
    const float* tcol = trans + lane;        // fwd: V[q][lane]
    const float* trow = trans + lane * 66;   // bwd: V[lane][q]
    (void)tcol; (void)trow;

    V_ALL(DECLV)
    if (FWD) { V_ALL(LOADF) } else { V_ALL(LOADB) }
    V_ALL(PINV)   // force all 64 into live, non-rematerializable VGPRs

    float a;
    int   K = 0;
    if (FWD) a = __builtin_amdgcn_exp2f((pb[0] + trans[64 * 66 + lane]) * L2E);
    else     a = __builtin_amdgcn_exp2f(trow[65] * L2E);

    const int dir = FWD ? 1 : -1;
    int n = FWD ? h - 1 : sl - h;
    int r = FWD ? 1 : sl - 1;

    float E0 = EXPE(ROWF(r)), E1 = EXPE(ROWF(r + dir)),
          E2 = EXPE(ROWF(r + 2 * dir)), E3 = EXPE(ROWF(r + 3 * dir));
    while (n >= 4) {
        float F0 = ROWF(r + 4 * dir), F1 = ROWF(r + 5 * dir),
              F2 = ROWF(r + 6 * dir), F3 = ROWF(r + 7 * dir);
        STEPN(E0) STEPN(E1) STEPN(E2) STEPN(E3)
        RENORM
        E0 = EXPE(F0); E1 = EXPE(F1); E2 = EXPE(F2); E3 = EXPE(F3);
        r += 4 * dir; n -= 4;
    }
    if (n > 0) { STEPN(E0) --n; }
    if (n > 0) { STEPN(E1) --n; }
    if (n > 0) { STEPN(E2) }
    RENORM

    wsV[b * 64 + lane] = a;
    if (lane == 0) wsK[b] = K;
}

__global__ __launch_bounds__(64) __attribute__((amdgpu_waves_per_eu(1, 1)))
void chain_kernel(const float* __restrict__ pred,
                  const float* __restrict__ trans,
                  const int*   __restrict__ ref,
                  const int*   __restrict__ seqlen,
                  float* __restrict__ wsA, float* __restrict__ wsB,
                  int* __restrict__ wsKf, int* __restrict__ wsKb,
                  float* __restrict__ out)
{
    const int role = blockIdx.x >> 8;
    const int b    = blockIdx.x & 255;
    const int lane = threadIdx.x;
    const int sl   = seqlen[b];
    const int h    = (sl + 1) >> 1;

    if (role == 0) {
        chain<true>(pred, trans, b, lane, sl, h, wsA, wsKf);
    } else if (role == 1) {
        chain<false>(pred, trans, b, lane, sl, h, wsB, wsKb);
    } else {
        // gold-path score
        const int*   rb = ref  + b * 1024;
        const float* pg = pred + (size_t)b * 65536;
        float acc = 0.f;
        for (int t = lane; t <= sl; t += 64) {
            int from = (t == 0) ? 64 : rb[t - 1];
            int cur  = (t < sl) ? rb[t] : 65;
            acc += trans[from * 66 + cur];
            if (t < sl) acc += pg[t * 64 + cur];
        }
        #pragma unroll
        for (int off = 32; off; off >>= 1) acc += __shfl_xor(acc, off, 64);
        if (lane == 0) atomicAdd(out, -acc);
    }
}

__global__ __launch_bounds__(64) void combine_kernel(
    const float* __restrict__ wsA, const float* __restrict__ wsB,
    const int* __restrict__ wsKf, const int* __restrict__ wsKb,
    float* __restrict__ out)
{
    const int b = blockIdx.x, lane = threadIdx.x;
    float z = wsA[b * 64 + lane] * wsB[b * 64 + lane];
    #pragma unroll
    for (int off = 32; off; off >>= 1) z += __shfl_xor(z, off, 64);
    if (lane == 0) {
        float res = LN2 * (__builtin_amdgcn_logf(z) + (float)(wsKf[b] + wsKb[b]));
        atomicAdd(out, res);
    }
}

extern "C" void kernel_launch(void* const* d_in, const int* in_sizes, int n_in,
                              void* d_out, int out_size, void* d_ws, size_t ws_size,
                              hipStream_t stream) {
    const float* pred   = (const float*)d_in[0];
    const float* trans  = (const float*)d_in[1];
    const int*   ref    = (const int*)d_in[2];
    const int*   seqlen = (const int*)d_in[3];
    float* out = (float*)d_out;

    float* wsA  = (float*)d_ws;            // 256*64 f32
    float* wsB  = wsA + 256 * 64;          // 256*64 f32
    int*   wsKf = (int*)(wsB + 256 * 64);  // 256 i32
    int*   wsKb = wsKf + 256;              // 256 i32

    hipMemsetAsync(out, 0, sizeof(float), stream);
    chain_kernel<<<768, 64, 0, stream>>>(pred, trans, ref, seqlen,
                                         wsA, wsB, wsKf, wsKb, out);
    combine_kernel<<<256, 64, 0, stream>>>(wsA, wsB, wsKf, wsKb, out);
}